// Round 1
// baseline (315.700 us; speedup 1.0000x reference)
//
#include <hip/hip_runtime.h>
#include <hip/hip_bf16.h>

// CIA_56049323213169: channel attention
//   x (4,1024,64,64) f32.  A = x viewed (1024,16384) [x_cn], B1 = x viewed (16384,1024) [x_nc]
//   S = A @ B1 (1024x1024); attn = softmax_rows(S)
//   out = attn @ A (1024x16384); y = softmax_rows(out)
//   result = x + softmax_over_W64(y)
// bf16 MFMA for both GEMMs (error damped: see round-0 analysis).

typedef __bf16 bf16x8 __attribute__((ext_vector_type(8)));
typedef float f32x4 __attribute__((ext_vector_type(4)));
typedef unsigned short u16;
typedef unsigned short u16x4 __attribute__((ext_vector_type(4)));
typedef unsigned short u16x8 __attribute__((ext_vector_type(8)));

#define DEV __device__ __forceinline__

DEV float bf2f(u16 u) { return __uint_as_float(((unsigned int)u) << 16); }
DEV u16 f2bf(float f) {  // RNE f32->bf16 (no NaN/Inf in this workload)
  unsigned int x = __float_as_uint(f);
  return (u16)((x + 0x7FFFu + ((x >> 16) & 1u)) >> 16);
}

DEV void gld16(const u16* g, u16* lds) {
  // async global->LDS, 16B per lane; LDS dest = wave-uniform base + lane*16
  __builtin_amdgcn_global_load_lds(
      (const __attribute__((address_space(1))) unsigned int*)g,
      (__attribute__((address_space(3))) unsigned int*)lds, 16, 0, 0);
}

// ---------------- prep: cast f32 -> bf16 (flat) ----------------
__global__ __launch_bounds__(256) void cast_f32_bf16(const float* __restrict__ in,
                                                     u16* __restrict__ out) {
  int i = (blockIdx.x * 256 + threadIdx.x) * 4;
  float4 v = *reinterpret_cast<const float4*>(in + i);
  u16x4 o;
  o[0] = f2bf(v.x); o[1] = f2bf(v.y); o[2] = f2bf(v.z); o[3] = f2bf(v.w);
  *reinterpret_cast<u16x4*>(out + i) = o;
}

// ---------------- prep: transpose + cast. in: (R,C) f32 -> out: (C,R) bf16 ----
__global__ __launch_bounds__(256) void transpose_cast(const float* __restrict__ in,
                                                      u16* __restrict__ out,
                                                      int R, int C) {
  __shared__ float tile[32][33];
  const int c0 = blockIdx.x * 32, r0 = blockIdx.y * 32;
  const int tx = threadIdx.x, ty = threadIdx.y;  // block (32,8)
#pragma unroll
  for (int j = 0; j < 4; ++j)
    tile[ty + j * 8][tx] = in[(size_t)(r0 + ty + j * 8) * C + c0 + tx];
  __syncthreads();
#pragma unroll
  for (int j = 0; j < 4; ++j)
    out[(size_t)(c0 + ty + j * 8) * R + r0 + tx] = f2bf(tile[tx][ty + j * 8]);
}

// ---------------- GEMM: C = A(MxK,lda) * Bt(NxK,ldbt)^T ----------------
// 128x128 tile, BK=32, 4 waves (2x2), mfma_f32_16x16x32_bf16, global_load_lds staging.
// SPLIT: grid.z slices K, writes f32 partials at Cout + z*M*N.
// OUTBF16: write bf16 C (no split).
template <bool SPLIT, bool OUTBF16>
__global__ __launch_bounds__(256) void gemm_bt(const u16* __restrict__ A,
                                               const u16* __restrict__ Bt,
                                               void* __restrict__ Cout,
                                               int M, int N, int Kslice,
                                               int lda, int ldbt) {
  __shared__ __align__(16) u16 As[128 * 32];
  __shared__ __align__(16) u16 Bs[128 * 32];
  const int tid = threadIdx.x;
  const int w = tid >> 6, l = tid & 63;
  const int wr = w >> 1, wc = w & 1;
  const int brow = blockIdx.y * 128, bcol = blockIdx.x * 128;
  const int kbase = SPLIT ? blockIdx.z * Kslice : 0;
  const int ksteps = Kslice >> 5;

  const int srow = w * 16 + (l >> 2);  // staging row (within a 64-row half)
  const int scol = (l & 3) * 8;        // staging k offset (8 bf16 = 16B)
  u16* AsW = As + (w * 16) * 32;       // wave-uniform LDS base
  u16* BsW = Bs + (w * 16) * 32;

  f32x4 acc[4][4];
#pragma unroll
  for (int m = 0; m < 4; ++m)
#pragma unroll
    for (int n = 0; n < 4; ++n) acc[m][n] = f32x4{0.f, 0.f, 0.f, 0.f};

  const int fr = l & 15, fg = l >> 4;  // fragment row-in-16, k-group

  for (int kt = 0; kt < ksteps; ++kt) {
    const int k0 = kbase + (kt << 5);
    gld16(A + (size_t)(brow + srow) * lda + k0 + scol, AsW);
    gld16(A + (size_t)(brow + 64 + srow) * lda + k0 + scol, AsW + 64 * 32);
    gld16(Bt + (size_t)(bcol + srow) * ldbt + k0 + scol, BsW);
    gld16(Bt + (size_t)(bcol + 64 + srow) * ldbt + k0 + scol, BsW + 64 * 32);
    __syncthreads();  // drains vmcnt -> LDS tiles complete

    bf16x8 af[4], bf[4];
#pragma unroll
    for (int m = 0; m < 4; ++m)
      af[m] = *reinterpret_cast<const bf16x8*>(As + (wr * 64 + m * 16 + fr) * 32 + fg * 8);
#pragma unroll
    for (int n = 0; n < 4; ++n)
      bf[n] = *reinterpret_cast<const bf16x8*>(Bs + (wc * 64 + n * 16 + fr) * 32 + fg * 8);
#pragma unroll
    for (int m = 0; m < 4; ++m)
#pragma unroll
      for (int n = 0; n < 4; ++n)
        acc[m][n] = __builtin_amdgcn_mfma_f32_16x16x32_bf16(af[m], bf[n], acc[m][n], 0, 0, 0);
    __syncthreads();  // protect LDS from next-iter staging
  }

  // epilogue: C/D layout col = lane&15, row = (lane>>4)*4 + j  [measured m89/m91]
  const int cbase = bcol + wc * 64 + fr;
  const int rbase = brow + wr * 64 + fg * 4;
  if (OUTBF16) {
    u16* Co = (u16*)Cout;
#pragma unroll
    for (int m = 0; m < 4; ++m)
#pragma unroll
      for (int n = 0; n < 4; ++n)
#pragma unroll
        for (int j = 0; j < 4; ++j)
          Co[(size_t)(rbase + m * 16 + j) * N + cbase + n * 16] = f2bf(acc[m][n][j]);
  } else {
    float* Cf = (float*)Cout + (SPLIT ? (size_t)blockIdx.z * M * N : 0);
#pragma unroll
    for (int m = 0; m < 4; ++m)
#pragma unroll
      for (int n = 0; n < 4; ++n)
#pragma unroll
        for (int j = 0; j < 4; ++j)
          Cf[(size_t)(rbase + m * 16 + j) * N + cbase + n * 16] = acc[m][n][j];
  }
}

// ---------------- softmax1: reduce 8 split-K partials + row softmax -> bf16 attn ----
__global__ __launch_bounds__(256) void softmax1(const float* __restrict__ Sp,
                                                u16* __restrict__ attn) {
  const int row = blockIdx.x, t = threadIdx.x;
  float4 s = {0.f, 0.f, 0.f, 0.f};
#pragma unroll
  for (int z = 0; z < 8; ++z) {
    float4 v = *reinterpret_cast<const float4*>(Sp + (size_t)z * 1024 * 1024 +
                                                (size_t)row * 1024 + t * 4);
    s.x += v.x; s.y += v.y; s.z += v.z; s.w += v.w;
  }
  __shared__ float red[256];
  red[t] = fmaxf(fmaxf(s.x, s.y), fmaxf(s.z, s.w));
  __syncthreads();
  for (int off = 128; off > 0; off >>= 1) {
    if (t < off) red[t] = fmaxf(red[t], red[t + off]);
    __syncthreads();
  }
  const float rowmax = red[0];
  __syncthreads();
  float e0 = __expf(s.x - rowmax), e1 = __expf(s.y - rowmax);
  float e2 = __expf(s.z - rowmax), e3 = __expf(s.w - rowmax);
  red[t] = e0 + e1 + e2 + e3;
  __syncthreads();
  for (int off = 128; off > 0; off >>= 1) {
    if (t < off) red[t] += red[t + off];
    __syncthreads();
  }
  const float inv = 1.0f / red[0];
  u16x4 o;
  o[0] = f2bf(e0 * inv); o[1] = f2bf(e1 * inv);
  o[2] = f2bf(e2 * inv); o[3] = f2bf(e3 * inv);
  *reinterpret_cast<u16x4*>(attn + (size_t)row * 1024 + t * 4) = o;
}

// ---------------- softmax2: row softmax over 16384 (bf16 in -> bf16 out) ----------
__global__ __launch_bounds__(1024) void softmax2(const u16* __restrict__ Sc,
                                                 u16* __restrict__ Y) {
  const int row = blockIdx.x, t = threadIdx.x;
  const size_t base = (size_t)row * 16384 + (size_t)t * 16;
  u16x8 u0 = *reinterpret_cast<const u16x8*>(Sc + base);
  u16x8 u1 = *reinterpret_cast<const u16x8*>(Sc + base + 8);
  float v[16];
#pragma unroll
  for (int j = 0; j < 8; ++j) { v[j] = bf2f(u0[j]); v[8 + j] = bf2f(u1[j]); }
  float m = v[0];
#pragma unroll
  for (int j = 1; j < 16; ++j) m = fmaxf(m, v[j]);
  __shared__ float red[1024];
  red[t] = m;
  __syncthreads();
  for (int off = 512; off > 0; off >>= 1) {
    if (t < off) red[t] = fmaxf(red[t], red[t + off]);
    __syncthreads();
  }
  const float rowmax = red[0];
  __syncthreads();
  float e[16], sum = 0.f;
#pragma unroll
  for (int j = 0; j < 16; ++j) { e[j] = __expf(v[j] - rowmax); sum += e[j]; }
  red[t] = sum;
  __syncthreads();
  for (int off = 512; off > 0; off >>= 1) {
    if (t < off) red[t] += red[t + off];
    __syncthreads();
  }
  const float inv = 1.0f / red[0];
  u16x8 o0, o1;
#pragma unroll
  for (int j = 0; j < 8; ++j) { o0[j] = f2bf(e[j] * inv); o1[j] = f2bf(e[8 + j] * inv); }
  *reinterpret_cast<u16x8*>(Y + base) = o0;
  *reinterpret_cast<u16x8*>(Y + base + 8) = o1;
}

// ---------------- final: out = x + softmax_over_64(y), wave per 64-group ---------
__global__ __launch_bounds__(256) void final_softmax_add(const u16* __restrict__ Y,
                                                         const float* __restrict__ X,
                                                         float* __restrict__ O) {
  const int i = blockIdx.x * 256 + threadIdx.x;
  const float y = bf2f(Y[i]);
  float m = y;
#pragma unroll
  for (int off = 32; off > 0; off >>= 1) m = fmaxf(m, __shfl_xor(m, off, 64));
  const float e = __expf(y - m);
  float s = e;
#pragma unroll
  for (int off = 32; off > 0; off >>= 1) s += __shfl_xor(s, off, 64);
  O[i] = X[i] + e / s;
}

extern "C" void kernel_launch(void* const* d_in, const int* in_sizes, int n_in,
                              void* d_out, int out_size, void* d_ws, size_t ws_size,
                              hipStream_t stream) {
  const float* x = (const float*)d_in[0];
  float* out = (float*)d_out;
  char* ws = (char*)d_ws;

  // Workspace layout (needs 98 MiB):
  //   P0 [ 0,32)MiB : A16 flat bf16 (x_cn rows); reused as bf16 scores after GEMM1
  //   P1 [32,64)MiB : Bt1 (1024x16384) then Bt2 (16384x1024)
  //   P2 [64,96)MiB : split-K f32 partials (8x1024x1024); reused as y16 after softmax1
  //   P3 [96,98)MiB : attn bf16 (1024x1024)
  const size_t MiB = 1u << 20;
  if (ws_size < 98 * MiB) return;  // fail visibly rather than corrupt
  u16* A16 = (u16*)(ws);
  u16* BtT = (u16*)(ws + 32 * MiB);
  float* Sp = (float*)(ws + 64 * MiB);
  u16* attn = (u16*)(ws + 96 * MiB);
  u16* Sc = A16;        // GEMM2 bf16 output (A16 dead after GEMM1)
  u16* Y = (u16*)Sp;    // softmax2 output (partials dead after softmax1)

  cast_f32_bf16<<<16384, 256, 0, stream>>>(x, A16);
  transpose_cast<<<dim3(32, 512), dim3(32, 8), 0, stream>>>(x, BtT, 16384, 1024);
  gemm_bt<true, false><<<dim3(8, 8, 8), 256, 0, stream>>>(
      A16, BtT, Sp, 1024, 1024, 2048, 16384, 16384);
  softmax1<<<1024, 256, 0, stream>>>(Sp, attn);
  transpose_cast<<<dim3(512, 32), dim3(32, 8), 0, stream>>>(x, BtT, 1024, 16384);
  gemm_bt<false, true><<<dim3(128, 8, 1), 256, 0, stream>>>(
      attn, BtT, Sc, 1024, 16384, 1024, 1024, 1024);
  softmax2<<<1024, 1024, 0, stream>>>(Sc, Y);
  final_softmax_add<<<65536, 256, 0, stream>>>(Y, x, out);
}

// Round 2
// 276.161 us; speedup vs baseline: 1.1432x; 1.1432x over previous
//
#include <hip/hip_runtime.h>
#include <hip/hip_bf16.h>

// CIA_56049323213169: channel attention
//   x (4,1024,64,64) f32.  A = x viewed (1024,16384) [x_cn], B1 = x viewed (16384,1024) [x_nc]
//   S = A @ B1 (1024x1024); attn = softmax_rows(S)
//   out = attn @ x_cn (1024x16384); y = softmax_rows(out)
//   result = x + softmax_over_W64(y)
// GEMMs: 256x256-tile 8-phase pipelined bf16 MFMA (T2 swizzle + T3/T4 counted vmcnt + T5 setprio).

typedef __bf16 bf16x8 __attribute__((ext_vector_type(8)));
typedef float f32x4 __attribute__((ext_vector_type(4)));
typedef unsigned short u16;
typedef unsigned short u16x4 __attribute__((ext_vector_type(4)));
typedef unsigned short u16x8 __attribute__((ext_vector_type(8)));

#define DEV __device__ __forceinline__

DEV float bf2f(u16 u) { return __uint_as_float(((unsigned int)u) << 16); }
DEV u16 f2bf(float f) {  // RNE f32->bf16 (no NaN/Inf in this workload)
  unsigned int x = __float_as_uint(f);
  return (u16)((x + 0x7FFFu + ((x >> 16) & 1u)) >> 16);
}

DEV void gld16(const u16* g, u16* lds) {
  // async global->LDS, 16B per lane; LDS dest = wave-uniform base + lane*16
  __builtin_amdgcn_global_load_lds(
      (const __attribute__((address_space(1))) unsigned int*)g,
      (__attribute__((address_space(3))) unsigned int*)lds, 16, 0, 0);
}

// ---------------- prep: cast f32 -> bf16 (flat) ----------------
__global__ __launch_bounds__(256) void cast_f32_bf16(const float* __restrict__ in,
                                                     u16* __restrict__ out) {
  int i = (blockIdx.x * 256 + threadIdx.x) * 4;
  float4 v = *reinterpret_cast<const float4*>(in + i);
  u16x4 o;
  o[0] = f2bf(v.x); o[1] = f2bf(v.y); o[2] = f2bf(v.z); o[3] = f2bf(v.w);
  *reinterpret_cast<u16x4*>(out + i) = o;
}

// ---------------- prep: transpose + cast. in: (R,C) f32 -> out: (C,R) bf16 ----
__global__ __launch_bounds__(256) void transpose_cast(const float* __restrict__ in,
                                                      u16* __restrict__ out,
                                                      int R, int C) {
  __shared__ float tile[32][33];
  const int c0 = blockIdx.x * 32, r0 = blockIdx.y * 32;
  const int tx = threadIdx.x, ty = threadIdx.y;  // block (32,8)
#pragma unroll
  for (int j = 0; j < 4; ++j)
    tile[ty + j * 8][tx] = in[(size_t)(r0 + ty + j * 8) * C + c0 + tx];
  __syncthreads();
#pragma unroll
  for (int j = 0; j < 4; ++j)
    out[(size_t)(c0 + ty + j * 8) * R + r0 + tx] = f2bf(tile[tx][ty + j * 8]);
}

// =====================================================================
// 256x256-tile 8-phase GEMM:  C = A(Mx*,lda) * Bt(Nx*,ldbt)^T over a
// 1024-wide K-slice (16 K-tiles of 64).  8 waves (2M x 4N), 512 threads.
// LDS: [buf][mat][khalf][256x32] = 128 KiB, XOR bank swizzle on 16B slots.
// Staggered staging: ph1->A-k1(t+1), ph2->B-k1(t+1), ph3->A-k0(t+2),
// ph4->B-k0(t+2); counted vmcnt(8) at ph2/ph4 (never 0 mid-loop).
// MODE 0 (GEMM1): grid 256 = 4x * 4y * 16z (split-K, bf16 partials)
// MODE 1 (GEMM2): grid 256 = 64x * 4y
// =====================================================================

#define FENCE() asm volatile("" ::: "memory")
#define BAR()                           \
  {                                     \
    FENCE();                            \
    __builtin_amdgcn_s_barrier();       \
    __builtin_amdgcn_sched_barrier(0);  \
    FENCE();                            \
  }
#define LGKM0()                                          \
  {                                                      \
    asm volatile("s_waitcnt lgkmcnt(0)" ::: "memory");   \
    __builtin_amdgcn_sched_barrier(0);                   \
  }

#define DS_A(BUF, H, MG)                                        \
  {                                                             \
    const u16* Ab_ = &lds[(BUF)][0][(H)][0] + aoff + (MG)*2048; \
    a[0] = *(const bf16x8*)(Ab_);                               \
    a[1] = *(const bf16x8*)(Ab_ + 512);                         \
    a[2] = *(const bf16x8*)(Ab_ + 1024);                        \
    a[3] = *(const bf16x8*)(Ab_ + 1536);                        \
  }
#define DS_B(BUF, H)                                            \
  {                                                             \
    const u16* Bb_ = &lds[(BUF)][1][(H)][0] + boff;             \
    b[0] = *(const bf16x8*)(Bb_);                               \
    b[1] = *(const bf16x8*)(Bb_ + 512);                         \
    b[2] = *(const bf16x8*)(Bb_ + 1024);                        \
    b[3] = *(const bf16x8*)(Bb_ + 1536);                        \
  }
#define STAGE(BUF, MAT, H, KCOL, P, LD)        \
  {                                            \
    u16* d_ = &lds[(BUF)][(MAT)][(H)][0];      \
    gld16((P) + (KCOL), d_ + wb0);             \
    gld16((P) + (KCOL) + (LD), d_ + wb1);      \
  }
#define MMA(MG)                                                              \
  {                                                                          \
    __builtin_amdgcn_s_setprio(1);                                           \
    _Pragma("unroll") for (int i_ = 0; i_ < 4; ++i_) {                       \
      _Pragma("unroll") for (int n_ = 0; n_ < 4; ++n_)                       \
        acc[(MG)*4 + i_][n_] = __builtin_amdgcn_mfma_f32_16x16x32_bf16(      \
            a[i_], b[n_], acc[(MG)*4 + i_][n_], 0, 0, 0);                    \
    }                                                                        \
    __builtin_amdgcn_s_setprio(0);                                           \
  }

// One K-tile = 4 phases. W2/W4 are vmcnt immediates (token-pasted).
#define TILE(BC, BN, T, DO_S12, DO_S34, W2, W4)                      \
  {                                                                  \
    /* ph1: h0, m0-3 */                                              \
    DS_A((BC), 0, 0); DS_B((BC), 0);                                 \
    if (DO_S12) STAGE((BN), 0, 1, ((T) + 1) * 64 + 32, pA, ldA128);  \
    BAR(); LGKM0(); MMA(0); BAR();                                   \
    /* ph2: h0, m4-7 */                                              \
    DS_A((BC), 0, 1);                                                \
    if (DO_S12) STAGE((BN), 1, 1, ((T) + 1) * 64 + 32, pB, ldB128);  \
    asm volatile("s_waitcnt vmcnt(" #W2 ")" ::: "memory");           \
    BAR(); LGKM0(); MMA(1); BAR();                                   \
    /* ph3: h1, m0-3 */                                              \
    DS_A((BC), 1, 0); DS_B((BC), 1);                                 \
    if (DO_S34) STAGE((BC), 0, 0, ((T) + 2) * 64, pA, ldA128);       \
    BAR(); LGKM0(); MMA(0); BAR();                                   \
    /* ph4: h1, m4-7 */                                              \
    DS_A((BC), 1, 1);                                                \
    if (DO_S34) STAGE((BC), 1, 0, ((T) + 2) * 64, pB, ldB128);       \
    asm volatile("s_waitcnt vmcnt(" #W4 ")" ::: "memory");           \
    BAR(); LGKM0(); MMA(1); BAR();                                   \
  }

template <int MODE>
__global__ __launch_bounds__(512, 2) void gemm256(const u16* __restrict__ A,
                                                  const u16* __restrict__ Bt,
                                                  u16* __restrict__ C,
                                                  int lda, int ldbt, int ldc,
                                                  long zstride) {
  __shared__ __align__(16) u16 lds[2][2][2][8192];  // 128 KiB

  const int tid = threadIdx.x;
  const int w = tid >> 6, l = tid & 63;
  const int wr = w >> 2, wc = w & 3;

  // block decomposition with XCD-chunked swizzle (256 % 8 == 0 -> bijective)
  const int hw = blockIdx.x;
  const int logical = ((hw & 7) << 5) | (hw >> 3);
  int bx, by, z;
  if (MODE == 0) { bx = logical & 3; by = (logical >> 2) & 3; z = logical >> 4; }
  else           { by = logical & 3; bx = logical >> 2;       z = 0; }
  const int brow = by * 256, bcol = bx * 256;
  const int kbase = z << 10;

  // staging addresses: lane l covers LDS (row = w*16 + issue*128 + l/4, slot = l&3)
  // source col pre-swizzled (inverse of read swizzle; XOR is an involution)
  const int srow = w * 16 + (l >> 2);
  const int swz = (((l & 3) ^ ((l >> 2) & 3) ^ ((l >> 4) & 1)) * 8);
  const u16* pA = A + (size_t)(brow + srow) * lda + kbase + swz;
  const u16* pB = Bt + (size_t)(bcol + srow) * ldbt + kbase + swz;
  const size_t ldA128 = (size_t)128 * lda, ldB128 = (size_t)128 * ldbt;
  const int wb0 = (w * 16) * 32, wb1 = (w * 16 + 128) * 32;

  // fragment read offsets (swizzled slot: fg ^ (row&3) ^ ((row>>2)&1))
  const int slotp = (l >> 4) ^ (l & 3) ^ ((l >> 2) & 1);
  const int aoff = (wr * 128 + (l & 15)) * 32 + slotp * 8;
  const int boff = (wc * 64 + (l & 15)) * 32 + slotp * 8;

  // ---- prologue: tile0 all 4 halves -> buf0; tile1 k0 halves -> buf1 ----
  STAGE(0, 0, 0, 0, pA, ldA128);
  STAGE(0, 1, 0, 0, pB, ldB128);
  STAGE(0, 0, 1, 32, pA, ldA128);
  STAGE(0, 1, 1, 32, pB, ldB128);
  STAGE(1, 0, 0, 64, pA, ldA128);
  STAGE(1, 1, 0, 64, pB, ldB128);

  f32x4 acc[8][4];
#pragma unroll
  for (int m = 0; m < 8; ++m)
#pragma unroll
    for (int n = 0; n < 4; ++n) acc[m][n] = f32x4{0.f, 0.f, 0.f, 0.f};

  bf16x8 a[4], b[4];

  asm volatile("s_waitcnt vmcnt(8)" ::: "memory");  // tile0 k0 halves resident
  BAR();

  // ---- main loop: 16 K-tiles, last two peeled for tail waits ----
#pragma unroll 1
  for (int t = 0; t < 14; ++t) {
    const int bc = t & 1;
    TILE(bc, bc ^ 1, t, 1, 1, 8, 8);
  }
  TILE(0, 1, 14, 1, 0, 8, 4);
  TILE(1, 0, 15, 0, 0, 0, 0);

  // ---- epilogue: C/D layout col = lane&15, row = (lane>>4)*4 + j ----
  u16* Cz = C + (size_t)z * zstride;
  const int er = brow + wr * 128 + ((l >> 4) << 2);
  const int ec = bcol + wc * 64 + (l & 15);
#pragma unroll
  for (int m = 0; m < 8; ++m)
#pragma unroll
    for (int n = 0; n < 4; ++n)
#pragma unroll
      for (int j = 0; j < 4; ++j)
        Cz[(size_t)(er + m * 16 + j) * ldc + ec + n * 16] = f2bf(acc[m][n][j]);
}

// ---------------- softmax1: reduce 16 split-K bf16 partials + row softmax -> bf16 attn
__global__ __launch_bounds__(256) void softmax1(const u16* __restrict__ Sp,
                                                u16* __restrict__ attn) {
  const int row = blockIdx.x, t = threadIdx.x;
  float s0 = 0.f, s1 = 0.f, s2 = 0.f, s3 = 0.f;
#pragma unroll
  for (int z = 0; z < 16; ++z) {
    u16x4 v = *reinterpret_cast<const u16x4*>(Sp + (size_t)z * 1024 * 1024 +
                                              (size_t)row * 1024 + t * 4);
    s0 += bf2f(v[0]); s1 += bf2f(v[1]); s2 += bf2f(v[2]); s3 += bf2f(v[3]);
  }
  __shared__ float red[256];
  red[t] = fmaxf(fmaxf(s0, s1), fmaxf(s2, s3));
  __syncthreads();
  for (int off = 128; off > 0; off >>= 1) {
    if (t < off) red[t] = fmaxf(red[t], red[t + off]);
    __syncthreads();
  }
  const float rowmax = red[0];
  __syncthreads();
  float e0 = __expf(s0 - rowmax), e1 = __expf(s1 - rowmax);
  float e2 = __expf(s2 - rowmax), e3 = __expf(s3 - rowmax);
  red[t] = e0 + e1 + e2 + e3;
  __syncthreads();
  for (int off = 128; off > 0; off >>= 1) {
    if (t < off) red[t] += red[t + off];
    __syncthreads();
  }
  const float inv = 1.0f / red[0];
  u16x4 o;
  o[0] = f2bf(e0 * inv); o[1] = f2bf(e1 * inv);
  o[2] = f2bf(e2 * inv); o[3] = f2bf(e3 * inv);
  *reinterpret_cast<u16x4*>(attn + (size_t)row * 1024 + t * 4) = o;
}

// ---------------- softmax2: row softmax over 16384 (bf16 in -> bf16 out) ----------
__global__ __launch_bounds__(1024) void softmax2(const u16* __restrict__ Sc,
                                                 u16* __restrict__ Y) {
  const int row = blockIdx.x, t = threadIdx.x;
  const size_t base = (size_t)row * 16384 + (size_t)t * 16;
  u16x8 u0 = *reinterpret_cast<const u16x8*>(Sc + base);
  u16x8 u1 = *reinterpret_cast<const u16x8*>(Sc + base + 8);
  float v[16];
#pragma unroll
  for (int j = 0; j < 8; ++j) { v[j] = bf2f(u0[j]); v[8 + j] = bf2f(u1[j]); }
  float m = v[0];
#pragma unroll
  for (int j = 1; j < 16; ++j) m = fmaxf(m, v[j]);
  __shared__ float red[1024];
  red[t] = m;
  __syncthreads();
  for (int off = 512; off > 0; off >>= 1) {
    if (t < off) red[t] = fmaxf(red[t], red[t + off]);
    __syncthreads();
  }
  const float rowmax = red[0];
  __syncthreads();
  float e[16], sum = 0.f;
#pragma unroll
  for (int j = 0; j < 16; ++j) { e[j] = __expf(v[j] - rowmax); sum += e[j]; }
  red[t] = sum;
  __syncthreads();
  for (int off = 512; off > 0; off >>= 1) {
    if (t < off) red[t] += red[t + off];
    __syncthreads();
  }
  const float inv = 1.0f / red[0];
  u16x8 o0, o1;
#pragma unroll
  for (int j = 0; j < 8; ++j) { o0[j] = f2bf(e[j] * inv); o1[j] = f2bf(e[8 + j] * inv); }
  *reinterpret_cast<u16x8*>(Y + base) = o0;
  *reinterpret_cast<u16x8*>(Y + base + 8) = o1;
}

// ---------------- final: out = x + softmax_over_64(y), wave per 64-group ---------
__global__ __launch_bounds__(256) void final_softmax_add(const u16* __restrict__ Y,
                                                         const float* __restrict__ X,
                                                         float* __restrict__ O) {
  const int i = blockIdx.x * 256 + threadIdx.x;
  const float y = bf2f(Y[i]);
  float m = y;
#pragma unroll
  for (int off = 32; off > 0; off >>= 1) m = fmaxf(m, __shfl_xor(m, off, 64));
  const float e = __expf(y - m);
  float s = e;
#pragma unroll
  for (int off = 32; off > 0; off >>= 1) s += __shfl_xor(s, off, 64);
  O[i] = X[i] + e / s;
}

extern "C" void kernel_launch(void* const* d_in, const int* in_sizes, int n_in,
                              void* d_out, int out_size, void* d_ws, size_t ws_size,
                              hipStream_t stream) {
  const float* x = (const float*)d_in[0];
  float* out = (float*)d_out;
  char* ws = (char*)d_ws;

  // Workspace layout (98 MiB):
  //   P0 [ 0,32): A16 (x as bf16, both GEMM1 operands' source); later Sc (GEMM2 out)
  //   P1 [32,64): Bt1 (1024x16384 bf16), later Bt2 (16384x1024 bf16)
  //   P2 [64,96): Sp16 split-K bf16 partials (16 x 1024x1024); later Y (softmax2 out)
  //   P3 [96,98): attn bf16 (1024x1024)
  const size_t MiB = 1u << 20;
  if (ws_size < 98 * MiB) return;  // fail visibly rather than corrupt
  u16* A16 = (u16*)(ws);
  u16* Bt1 = (u16*)(ws + 32 * MiB);  // also Bt2 region
  u16* Sp16 = (u16*)(ws + 64 * MiB);
  u16* attn = (u16*)(ws + 96 * MiB);
  u16* Sc = A16;          // GEMM2 bf16 scores (A16 dead by then)
  u16* Y = Sp16;          // softmax2 output (partials dead)

  cast_f32_bf16<<<16384, 256, 0, stream>>>(x, A16);
  transpose_cast<<<dim3(32, 512), dim3(32, 8), 0, stream>>>(x, Bt1, 16384, 1024);
  // GEMM1: S = x_cn @ x_nc, split-K 16, bf16 partials
  gemm256<0><<<256, 512, 0, stream>>>(A16, Bt1, Sp16, 16384, 16384, 1024,
                                      (long)1024 * 1024);
  softmax1<<<1024, 256, 0, stream>>>(Sp16, attn);
  transpose_cast<<<dim3(512, 32), dim3(32, 8), 0, stream>>>(x, Bt1, 1024, 16384);
  // GEMM2: out = attn @ x_cn
  gemm256<1><<<256, 512, 0, stream>>>(attn, Bt1, Sc, 1024, 1024, 16384, 0);
  softmax2<<<1024, 1024, 0, stream>>>(Sc, Y);
  final_softmax_add<<<65536, 256, 0, stream>>>(Y, x, out);
}

// Round 5
// 236.908 us; speedup vs baseline: 1.3326x; 1.1657x over previous
//
#include <hip/hip_runtime.h>
#include <hip/hip_bf16.h>

// CIA_56049323213169: channel attention
//   x (4,1024,64,64) f32.  X1 = flat viewed (1024,16384), X2 = flat viewed (16384,1024)
//   S = X1 @ X2 (1024x1024); attn = softmax_rows(S)
//   out = attn @ X1 (1024x16384); y = softmax_rows(out)
//   result = x + softmax_over_W64(y)   [W-groups = consecutive 64-elem chunks of flat]
// GEMMs: 256x256-tile 8-phase pipelined bf16 MFMA (T2 swizzle + T3/T4 counted vmcnt + T5).
// Round 3 kernel, resubmitted (rounds 3+4 were broker timeouts, no data):
//   fused W-softmax+residual into row-softmax kernel (Y buffer eliminated);
//   prep emits A16 during transpose1; transpose2 reads bf16.

typedef __bf16 bf16x8 __attribute__((ext_vector_type(8)));
typedef float f32x4 __attribute__((ext_vector_type(4)));
typedef unsigned short u16;
typedef unsigned short u16x4 __attribute__((ext_vector_type(4)));
typedef unsigned short u16x8 __attribute__((ext_vector_type(8)));

#define DEV __device__ __forceinline__

DEV float bf2f(u16 u) { return __uint_as_float(((unsigned int)u) << 16); }
DEV u16 f2bf(float f) {  // RNE f32->bf16 (no NaN/Inf in this workload)
  unsigned int x = __float_as_uint(f);
  return (u16)((x + 0x7FFFu + ((x >> 16) & 1u)) >> 16);
}

DEV void gld16(const u16* g, u16* lds) {
  // async global->LDS, 16B per lane; LDS dest = wave-uniform base + lane*16
  __builtin_amdgcn_global_load_lds(
      (const __attribute__((address_space(1))) unsigned int*)g,
      (__attribute__((address_space(3))) unsigned int*)lds, 16, 0, 0);
}

// ---- prep: read x as (16384,1024) f32; emit A16 (straight cast) + Bt1 (transpose) ----
__global__ __launch_bounds__(512) void prep_t1(const float* __restrict__ x,
                                               u16* __restrict__ A16,
                                               u16* __restrict__ Bt1) {
  __shared__ float tile[64][65];
  const int c0 = blockIdx.x * 64, r0 = blockIdx.y * 64;
  const int tx = threadIdx.x, ty = threadIdx.y;  // block (64,8)
#pragma unroll
  for (int j = 0; j < 8; ++j) {
    const size_t idx = (size_t)(r0 + ty + j * 8) * 1024 + c0 + tx;
    float v = x[idx];
    tile[ty + j * 8][tx] = v;
    A16[idx] = f2bf(v);
  }
  __syncthreads();
#pragma unroll
  for (int j = 0; j < 8; ++j)
    Bt1[(size_t)(c0 + ty + j * 8) * 16384 + r0 + tx] = f2bf(tile[tx][ty + j * 8]);
}

// ---- transpose2: A16 viewed (1024,16384) bf16 -> Bt2 (16384,1024) bf16 ----
__global__ __launch_bounds__(512) void t2_bf16(const u16* __restrict__ in,
                                               u16* __restrict__ out) {
  __shared__ u16 tile[64][68];  // stride 136B -> 2-way bank alias on column read (free)
  const int c0 = blockIdx.x * 64, r0 = blockIdx.y * 64;
  const int tx = threadIdx.x, ty = threadIdx.y;  // block (64,8)
#pragma unroll
  for (int j = 0; j < 8; ++j)
    tile[ty + j * 8][tx] = in[(size_t)(r0 + ty + j * 8) * 16384 + c0 + tx];
  __syncthreads();
#pragma unroll
  for (int j = 0; j < 8; ++j)
    out[(size_t)(c0 + ty + j * 8) * 1024 + r0 + tx] = tile[tx][ty + j * 8];
}

// =====================================================================
// 256x256-tile 8-phase GEMM (unchanged from round 2; see header comment)
// =====================================================================

#define FENCE() asm volatile("" ::: "memory")
#define BAR()                           \
  {                                     \
    FENCE();                            \
    __builtin_amdgcn_s_barrier();       \
    __builtin_amdgcn_sched_barrier(0);  \
    FENCE();                            \
  }
#define LGKM0()                                          \
  {                                                      \
    asm volatile("s_waitcnt lgkmcnt(0)" ::: "memory");   \
    __builtin_amdgcn_sched_barrier(0);                   \
  }

#define DS_A(BUF, H, MG)                                        \
  {                                                             \
    const u16* Ab_ = &lds[(BUF)][0][(H)][0] + aoff + (MG)*2048; \
    a[0] = *(const bf16x8*)(Ab_);                               \
    a[1] = *(const bf16x8*)(Ab_ + 512);                         \
    a[2] = *(const bf16x8*)(Ab_ + 1024);                        \
    a[3] = *(const bf16x8*)(Ab_ + 1536);                        \
  }
#define DS_B(BUF, H)                                            \
  {                                                             \
    const u16* Bb_ = &lds[(BUF)][1][(H)][0] + boff;             \
    b[0] = *(const bf16x8*)(Bb_);                               \
    b[1] = *(const bf16x8*)(Bb_ + 512);                         \
    b[2] = *(const bf16x8*)(Bb_ + 1024);                        \
    b[3] = *(const bf16x8*)(Bb_ + 1536);                        \
  }
#define STAGE(BUF, MAT, H, KCOL, P, LD)        \
  {                                            \
    u16* d_ = &lds[(BUF)][(MAT)][(H)][0];      \
    gld16((P) + (KCOL), d_ + wb0);             \
    gld16((P) + (KCOL) + (LD), d_ + wb1);      \
  }
#define MMA(MG)                                                              \
  {                                                                          \
    __builtin_amdgcn_s_setprio(1);                                           \
    _Pragma("unroll") for (int i_ = 0; i_ < 4; ++i_) {                       \
      _Pragma("unroll") for (int n_ = 0; n_ < 4; ++n_)                       \
        acc[(MG)*4 + i_][n_] = __builtin_amdgcn_mfma_f32_16x16x32_bf16(      \
            a[i_], b[n_], acc[(MG)*4 + i_][n_], 0, 0, 0);                    \
    }                                                                        \
    __builtin_amdgcn_s_setprio(0);                                           \
  }

// One K-tile = 4 phases. W2/W4 are vmcnt immediates (token-pasted).
#define TILE(BC, BN, T, DO_S12, DO_S34, W2, W4)                      \
  {                                                                  \
    DS_A((BC), 0, 0); DS_B((BC), 0);                                 \
    if (DO_S12) STAGE((BN), 0, 1, ((T) + 1) * 64 + 32, pA, ldA128);  \
    BAR(); LGKM0(); MMA(0); BAR();                                   \
    DS_A((BC), 0, 1);                                                \
    if (DO_S12) STAGE((BN), 1, 1, ((T) + 1) * 64 + 32, pB, ldB128);  \
    asm volatile("s_waitcnt vmcnt(" #W2 ")" ::: "memory");           \
    BAR(); LGKM0(); MMA(1); BAR();                                   \
    DS_A((BC), 1, 0); DS_B((BC), 1);                                 \
    if (DO_S34) STAGE((BC), 0, 0, ((T) + 2) * 64, pA, ldA128);       \
    BAR(); LGKM0(); MMA(0); BAR();                                   \
    DS_A((BC), 1, 1);                                                \
    if (DO_S34) STAGE((BC), 1, 0, ((T) + 2) * 64, pB, ldB128);       \
    asm volatile("s_waitcnt vmcnt(" #W4 ")" ::: "memory");           \
    BAR(); LGKM0(); MMA(1); BAR();                                   \
  }

template <int MODE>
__global__ __launch_bounds__(512, 2) void gemm256(const u16* __restrict__ A,
                                                  const u16* __restrict__ Bt,
                                                  u16* __restrict__ C,
                                                  int lda, int ldbt, int ldc,
                                                  long zstride) {
  __shared__ __align__(16) u16 lds[2][2][2][8192];  // 128 KiB

  const int tid = threadIdx.x;
  const int w = tid >> 6, l = tid & 63;
  const int wr = w >> 2, wc = w & 3;

  // block decomposition with XCD-chunked swizzle (256 % 8 == 0 -> bijective)
  const int hw = blockIdx.x;
  const int logical = ((hw & 7) << 5) | (hw >> 3);
  int bx, by, z;
  if (MODE == 0) { bx = logical & 3; by = (logical >> 2) & 3; z = logical >> 4; }
  else           { by = logical & 3; bx = logical >> 2;       z = 0; }
  const int brow = by * 256, bcol = bx * 256;
  const int kbase = z << 10;

  const int srow = w * 16 + (l >> 2);
  const int swz = (((l & 3) ^ ((l >> 2) & 3) ^ ((l >> 4) & 1)) * 8);
  const u16* pA = A + (size_t)(brow + srow) * lda + kbase + swz;
  const u16* pB = Bt + (size_t)(bcol + srow) * ldbt + kbase + swz;
  const size_t ldA128 = (size_t)128 * lda, ldB128 = (size_t)128 * ldbt;
  const int wb0 = (w * 16) * 32, wb1 = (w * 16 + 128) * 32;

  const int slotp = (l >> 4) ^ (l & 3) ^ ((l >> 2) & 1);
  const int aoff = (wr * 128 + (l & 15)) * 32 + slotp * 8;
  const int boff = (wc * 64 + (l & 15)) * 32 + slotp * 8;

  STAGE(0, 0, 0, 0, pA, ldA128);
  STAGE(0, 1, 0, 0, pB, ldB128);
  STAGE(0, 0, 1, 32, pA, ldA128);
  STAGE(0, 1, 1, 32, pB, ldB128);
  STAGE(1, 0, 0, 64, pA, ldA128);
  STAGE(1, 1, 0, 64, pB, ldB128);

  f32x4 acc[8][4];
#pragma unroll
  for (int m = 0; m < 8; ++m)
#pragma unroll
    for (int n = 0; n < 4; ++n) acc[m][n] = f32x4{0.f, 0.f, 0.f, 0.f};

  bf16x8 a[4], b[4];

  asm volatile("s_waitcnt vmcnt(8)" ::: "memory");
  BAR();

#pragma unroll 1
  for (int t = 0; t < 14; ++t) {
    const int bc = t & 1;
    TILE(bc, bc ^ 1, t, 1, 1, 8, 8);
  }
  TILE(0, 1, 14, 1, 0, 8, 4);
  TILE(1, 0, 15, 0, 0, 0, 0);

  u16* Cz = C + (size_t)z * zstride;
  const int er = brow + wr * 128 + ((l >> 4) << 2);
  const int ec = bcol + wc * 64 + (l & 15);
#pragma unroll
  for (int m = 0; m < 8; ++m)
#pragma unroll
    for (int n = 0; n < 4; ++n)
#pragma unroll
      for (int j = 0; j < 4; ++j)
        Cz[(size_t)(er + m * 16 + j) * ldc + ec + n * 16] = f2bf(acc[m][n][j]);
}

// ---- softmax1: reduce 16 split-K bf16 partials + row softmax -> bf16 attn ----
__global__ __launch_bounds__(256) void softmax1(const u16* __restrict__ Sp,
                                                u16* __restrict__ attn) {
  const int row = blockIdx.x, t = threadIdx.x;
  float s0 = 0.f, s1 = 0.f, s2 = 0.f, s3 = 0.f;
#pragma unroll
  for (int z = 0; z < 16; ++z) {
    u16x4 v = *reinterpret_cast<const u16x4*>(Sp + (size_t)z * 1024 * 1024 +
                                              (size_t)row * 1024 + t * 4);
    s0 += bf2f(v[0]); s1 += bf2f(v[1]); s2 += bf2f(v[2]); s3 += bf2f(v[3]);
  }
  __shared__ float red[256];
  red[t] = fmaxf(fmaxf(s0, s1), fmaxf(s2, s3));
  __syncthreads();
  for (int off = 128; off > 0; off >>= 1) {
    if (t < off) red[t] = fmaxf(red[t], red[t + off]);
    __syncthreads();
  }
  const float rowmax = red[0];
  __syncthreads();
  float e0 = __expf(s0 - rowmax), e1 = __expf(s1 - rowmax);
  float e2 = __expf(s2 - rowmax), e3 = __expf(s3 - rowmax);
  red[t] = e0 + e1 + e2 + e3;
  __syncthreads();
  for (int off = 128; off > 0; off >>= 1) {
    if (t < off) red[t] += red[t + off];
    __syncthreads();
  }
  const float inv = 1.0f / red[0];
  u16x4 o;
  o[0] = f2bf(e0 * inv); o[1] = f2bf(e1 * inv);
  o[2] = f2bf(e2 * inv); o[3] = f2bf(e3 * inv);
  *reinterpret_cast<u16x4*>(attn + (size_t)row * 1024 + t * 4) = o;
}

// ---- softmax2_final: row softmax over 16384, then per-64-group softmax + residual ----
// Row r of Sc holds 16384 consecutive flat elems = 256 W-groups of 64.
// Thread t owns elems [t*16, t*16+16); a W-group = 4 adjacent lanes.
__global__ __launch_bounds__(1024) void softmax2_final(const u16* __restrict__ Sc,
                                                       const float* __restrict__ X,
                                                       float* __restrict__ O) {
  const int row = blockIdx.x, t = threadIdx.x;
  const size_t base = (size_t)row * 16384 + (size_t)t * 16;
  u16x8 u0 = *reinterpret_cast<const u16x8*>(Sc + base);
  u16x8 u1 = *reinterpret_cast<const u16x8*>(Sc + base + 8);
  float v[16];
#pragma unroll
  for (int j = 0; j < 8; ++j) { v[j] = bf2f(u0[j]); v[8 + j] = bf2f(u1[j]); }
  float m = v[0];
#pragma unroll
  for (int j = 1; j < 16; ++j) m = fmaxf(m, v[j]);
  __shared__ float red[1024];
  red[t] = m;
  __syncthreads();
  for (int off = 512; off > 0; off >>= 1) {
    if (t < off) red[t] = fmaxf(red[t], red[t + off]);
    __syncthreads();
  }
  const float rowmax = red[0];
  __syncthreads();
  float e[16], sum = 0.f;
#pragma unroll
  for (int j = 0; j < 16; ++j) { e[j] = __expf(v[j] - rowmax); sum += e[j]; }
  red[t] = sum;
  __syncthreads();
  for (int off = 512; off > 0; off >>= 1) {
    if (t < off) red[t] += red[t + off];
    __syncthreads();
  }
  const float inv = 1.0f / red[0];  // y[j] = e[j] * inv

  // ---- fused: softmax over each 64-group (4 adjacent lanes) + residual add ----
  float em = e[0];
#pragma unroll
  for (int j = 1; j < 16; ++j) em = fmaxf(em, e[j]);
  em = fmaxf(em, __shfl_xor(em, 1, 64));
  em = fmaxf(em, __shfl_xor(em, 2, 64));
  const float ym = em * inv;  // group max of y

  float eg[16], sg = 0.f;
#pragma unroll
  for (int j = 0; j < 16; ++j) { eg[j] = __expf(e[j] * inv - ym); sg += eg[j]; }
  sg += __shfl_xor(sg, 1, 64);
  sg += __shfl_xor(sg, 2, 64);
  const float inv2 = 1.0f / sg;

#pragma unroll
  for (int q = 0; q < 4; ++q) {
    float4 xv = *reinterpret_cast<const float4*>(X + base + q * 4);
    float4 o;
    o.x = xv.x + eg[q * 4 + 0] * inv2;
    o.y = xv.y + eg[q * 4 + 1] * inv2;
    o.z = xv.z + eg[q * 4 + 2] * inv2;
    o.w = xv.w + eg[q * 4 + 3] * inv2;
    *reinterpret_cast<float4*>(O + base + q * 4) = o;
  }
}

extern "C" void kernel_launch(void* const* d_in, const int* in_sizes, int n_in,
                              void* d_out, int out_size, void* d_ws, size_t ws_size,
                              hipStream_t stream) {
  const float* x = (const float*)d_in[0];
  float* out = (float*)d_out;
  char* ws = (char*)d_ws;

  // Workspace layout (98 MiB):
  //   P0 [ 0,32): A16 (x as bf16); after transpose2 it's dead -> Sc (GEMM2 out)
  //   P1 [32,64): Bt1 (1024x16384), then Bt2 (16384x1024)
  //   P2 [64,96): Sp16 split-K bf16 partials (16 x 1024x1024); dead after softmax1
  //   P3 [96,98): attn bf16 (1024x1024)
  const size_t MiB = 1u << 20;
  if (ws_size < 98 * MiB) return;
  u16* A16 = (u16*)(ws);
  u16* Bt = (u16*)(ws + 32 * MiB);
  u16* Sp16 = (u16*)(ws + 64 * MiB);
  u16* attn = (u16*)(ws + 96 * MiB);
  u16* Sc = A16;  // GEMM2 output overlays A16 (dead by then)

  // prep: x viewed (16384,1024) -> A16 (cast) + Bt1 (transpose)
  prep_t1<<<dim3(16, 256), dim3(64, 8), 0, stream>>>(x, A16, Bt);
  // GEMM1: S = X1 @ X2, split-K 16, bf16 partials
  gemm256<0><<<256, 512, 0, stream>>>(A16, Bt, Sp16, 16384, 16384, 1024,
                                      (long)1024 * 1024);
  softmax1<<<1024, 256, 0, stream>>>(Sp16, attn);
  // transpose2: A16 viewed (1024,16384) -> Bt2 (16384,1024)
  t2_bf16<<<dim3(256, 16), dim3(64, 8), 0, stream>>>(A16, Bt);
  // GEMM2: out = attn @ X1
  gemm256<1><<<256, 512, 0, stream>>>(attn, Bt, Sc, 1024, 1024, 16384, 0);
  // row softmax + fused W-softmax + residual
  softmax2_final<<<1024, 1024, 0, stream>>>(Sc, x, out);
}